// Round 1
// baseline (1575.656 us; speedup 1.0000x reference)
//
#include <hip/hip_runtime.h>
#include <float.h>

// Problem constants (from reference)
#define NUM_Q 8
#define BN    8192      // B*N tokens
#define D     512
#define C     1024

// Layer-kernel tiling
#define TPB     32            // tokens per block
#define THREADS 512           // 8 waves
#define BK      16
#define CCHUNK  512
#define NCHUNK  (C / CCHUNK)  // 2
#define NKB     (D / BK)      // 32 k-blocks per chunk

// d_out layout (floats): [quantized_out | indices(as float) | losses]
#define QOUT_OFF 0
#define IDX_OFF  (BN * D)                 // 4194304
#define LOSS_OFF (IDX_OFF + BN * NUM_Q)   // 4259840

// ---------------------------------------------------------------------------
// init: residual R (stored in d_out quantized region) = x; zero loss slots
// ---------------------------------------------------------------------------
__global__ void rvq_init_kernel(const float* __restrict__ x, float* __restrict__ out) {
    int i = blockIdx.x * blockDim.x + threadIdx.x;
    const float4* x4 = (const float4*)x;
    float4* r4 = (float4*)(out + QOUT_OFF);
    const int n4 = BN * D / 4;
    for (int k = i; k < n4; k += gridDim.x * blockDim.x)
        r4[k] = x4[k];
    if (i < NUM_Q) out[LOSS_OFF + i] = 0.0f;
}

// ---------------------------------------------------------------------------
// One VQ layer: dist-GEMM + argmin + residual update + loss partial
//   block: 32 tokens x all 1024 codewords; 512 threads
//   thread tile: 4 tokens x 8 codewords (4 + 4 split across chunk halves)
// ---------------------------------------------------------------------------
__global__ __launch_bounds__(THREADS) void rvq_layer_kernel(
    const float* __restrict__ cb,   // this layer's codebook [C][D]
    float* __restrict__ out,        // d_out base
    int q)
{
    __shared__ float As[TPB][BK + 4];       // token-major, [32][20]
    __shared__ float Bs[BK][CCHUNK + 4];    // k-major,    [16][516]
    __shared__ float e2sh[CCHUNK];
    __shared__ int   bestIdxSh[TPB];
    __shared__ float lsum[THREADS / 64];

    float* R       = out + QOUT_OFF;   // residual lives in the quantized region
    float* idxOut  = out + IDX_OFF;
    float* lossAcc = out + LOSS_OFF + q;

    const int tid  = threadIdx.x;
    const int tx   = tid & 63;   // codeword dim within wave
    const int ty   = tid >> 6;   // wave id 0..7 -> tokens 4*ty .. 4*ty+3
    const int tok0 = blockIdx.x * TPB;

    float bestS[4];
    int   bestI[4];
#pragma unroll
    for (int j = 0; j < 4; ++j) { bestS[j] = FLT_MAX; bestI[j] = 0; }

    for (int chunk = 0; chunk < NCHUNK; ++chunk) {
        const int c0 = chunk * CCHUNK;
        float acc[4][8];
#pragma unroll
        for (int j = 0; j < 4; ++j)
#pragma unroll
            for (int m = 0; m < 8; ++m) acc[j][m] = 0.0f;

        float e2acc = 0.0f;
        const float* cbrow = cb + (size_t)(c0 + tid) * D;  // this thread's staged row

        for (int kb = 0; kb < NKB; ++kb) {
            const int kc = kb * BK;
            // ---- stage A (32 tokens x 16 k), vectorized, no transpose ----
            if (tid < 128) {
                int t  = tid >> 2;
                int kq = tid & 3;
                float4 v = *(const float4*)&R[(size_t)(tok0 + t) * D + kc + kq * 4];
                *(float4*)&As[t][kq * 4] = v;
            }
            // ---- stage B (512 codewords x 16 k), transpose to k-major; fold e2 ----
#pragma unroll
            for (int kq = 0; kq < 4; ++kq) {
                float4 v = *(const float4*)&cbrow[kc + kq * 4];
                Bs[kq * 4 + 0][tid] = v.x;
                Bs[kq * 4 + 1][tid] = v.y;
                Bs[kq * 4 + 2][tid] = v.z;
                Bs[kq * 4 + 3][tid] = v.w;
                e2acc += v.x * v.x + v.y * v.y + v.z * v.z + v.w * v.w;
            }
            __syncthreads();
            // ---- compute: per k: 1 b128 B-read x2 halves, A broadcast reads ----
#pragma unroll
            for (int k4 = 0; k4 < BK; k4 += 4) {
                float4 a0 = *(const float4*)&As[ty * 4 + 0][k4];
                float4 a1 = *(const float4*)&As[ty * 4 + 1][k4];
                float4 a2 = *(const float4*)&As[ty * 4 + 2][k4];
                float4 a3 = *(const float4*)&As[ty * 4 + 3][k4];
#pragma unroll
                for (int kk = 0; kk < 4; ++kk) {
                    // conflict-free: lanes read consecutive float4s in each half
                    float4 b0 = *(const float4*)&Bs[k4 + kk][tx * 4];
                    float4 b1 = *(const float4*)&Bs[k4 + kk][256 + tx * 4];
                    float bb[8] = { b0.x, b0.y, b0.z, b0.w, b1.x, b1.y, b1.z, b1.w };
                    float as[4] = { ((const float*)&a0)[kk], ((const float*)&a1)[kk],
                                    ((const float*)&a2)[kk], ((const float*)&a3)[kk] };
#pragma unroll
                    for (int j = 0; j < 4; ++j)
#pragma unroll
                        for (int m = 0; m < 8; ++m)
                            acc[j][m] += as[j] * bb[m];
                }
            }
            __syncthreads();
        }

        // publish e2 for this chunk
        e2sh[tid] = e2acc;
        __syncthreads();

        // ---- scores + argmin (score = e2 - 2*dot; r2 constant per token) ----
#pragma unroll
        for (int j = 0; j < 4; ++j) {
            float ls = FLT_MAX;
            int   li = 0x7fffffff;
#pragma unroll
            for (int m = 0; m < 8; ++m) {
                int cloc = (m < 4) ? (tx * 4 + m) : (256 + tx * 4 + (m - 4));
                float s = e2sh[cloc] - 2.0f * acc[j][m];
                int c = c0 + cloc;
                if (s < ls || (s == ls && c < li)) { ls = s; li = c; }
            }
            // wave reduce, first-index tie-break (matches jnp.argmin)
            for (int off = 32; off >= 1; off >>= 1) {
                float os = __shfl_down(ls, off, 64);
                int   oi = __shfl_down(li, off, 64);
                if (os < ls || (os == ls && oi < li)) { ls = os; li = oi; }
            }
            if (tx == 0) {
                if (ls < bestS[j] || (ls == bestS[j] && li < bestI[j])) {
                    bestS[j] = ls; bestI[j] = li;
                }
            }
        }
        __syncthreads();   // protect e2sh/Bs reuse across chunks
    }

    if (tx == 0) {
#pragma unroll
        for (int j = 0; j < 4; ++j) bestIdxSh[ty * 4 + j] = bestI[j];
    }
    __syncthreads();

    // ---- residual update + loss partial: 16 threads per token ----
    const int t = tid >> 4;
    const int g = tid & 15;
    const int best = bestIdxSh[t];
    const float* crow = cb + (size_t)best * D;
    float* rrow = R + (size_t)(tok0 + t) * D;
    float ss = 0.0f;
#pragma unroll
    for (int m = 0; m < 8; ++m) {
        int off = (m * 16 + g) * 4;
        float4 r = *(const float4*)&rrow[off];
        float4 c = *(const float4*)&crow[off];
        float4 nr = make_float4(r.x - c.x, r.y - c.y, r.z - c.z, r.w - c.w);
        *(float4*)&rrow[off] = nr;
        ss += nr.x * nr.x + nr.y * nr.y + nr.z * nr.z + nr.w * nr.w;
    }
    if (g == 0) idxOut[(size_t)(tok0 + t) * NUM_Q + q] = (float)best;

    for (int off = 32; off >= 1; off >>= 1)
        ss += __shfl_down(ss, off, 64);
    if (tx == 0) lsum[ty] = ss;
    __syncthreads();
    if (tid == 0) {
        float tot = 0.0f;
#pragma unroll
        for (int w = 0; w < THREADS / 64; ++w) tot += lsum[w];
        atomicAdd(lossAcc, tot);
    }
}

// ---------------------------------------------------------------------------
// finalize: quantized_out = x - residual_final (in place); scale losses
// ---------------------------------------------------------------------------
__global__ void rvq_finalize_kernel(const float* __restrict__ x, float* __restrict__ out) {
    int i = blockIdx.x * blockDim.x + threadIdx.x;
    const float4* x4 = (const float4*)x;
    float4* o4 = (float4*)(out + QOUT_OFF);
    const int n4 = BN * D / 4;
    for (int k = i; k < n4; k += gridDim.x * blockDim.x) {
        float4 xv = x4[k];
        float4 rv = o4[k];
        o4[k] = make_float4(xv.x - rv.x, xv.y - rv.y, xv.z - rv.z, xv.w - rv.w);
    }
    if (i < NUM_Q) out[LOSS_OFF + i] *= (1.0f / (float)(BN * D));
}

extern "C" void kernel_launch(void* const* d_in, const int* in_sizes, int n_in,
                              void* d_out, int out_size, void* d_ws, size_t ws_size,
                              hipStream_t stream) {
    const float* x   = (const float*)d_in[0];
    const float* cbs = (const float*)d_in[1];
    float* out = (float*)d_out;

    hipLaunchKernelGGL(rvq_init_kernel, dim3(1024), dim3(256), 0, stream, x, out);
    for (int q = 0; q < NUM_Q; ++q) {
        hipLaunchKernelGGL(rvq_layer_kernel, dim3(BN / TPB), dim3(THREADS), 0, stream,
                           cbs + (size_t)q * C * D, out, q);
    }
    hipLaunchKernelGGL(rvq_finalize_kernel, dim3(1024), dim3(256), 0, stream, x, out);
}

// Round 2
// 455.054 us; speedup vs baseline: 3.4626x; 3.4626x over previous
//
#include <hip/hip_runtime.h>
#include <float.h>

// Problem constants
#define NUM_Q 8
#define BN    8192      // B*N tokens
#define D     512
#define C     1024

// d_out layout (floats): [quantized_out | indices(as float) | losses]
#define QOUT_OFF 0
#define IDX_OFF  (BN * D)
#define LOSS_OFF (IDX_OFF + BN * NUM_Q)

// d_ws layout (bytes)
#define WIN_OFF_B  0                     // unsigned long long winners[8192]
#define E2_OFF_B   (BN * 8)              // float e2[NUM_Q*C] at byte 65536

typedef _Float16 f16x8 __attribute__((ext_vector_type(8)));
typedef float    f32x4 __attribute__((ext_vector_type(4)));

// GEMM tiling
#define TM  128
#define TN  128
#define BKK 32
#define LDK 40          // padded k-stride in elems (80 B -> conflict-light)
#define GTHREADS 512

__device__ __forceinline__ unsigned fkey(float f) {
    unsigned u = __float_as_uint(f);
    return (u & 0x80000000u) ? ~u : (u | 0x80000000u);
}

__device__ __forceinline__ unsigned long long u64min(unsigned long long a, unsigned long long b) {
    return a < b ? a : b;
}

__device__ __forceinline__ unsigned long long shfl_xor_u64(unsigned long long v, int m) {
    int lo = __shfl_xor((int)(unsigned)v, m, 64);
    int hi = __shfl_xor((int)(unsigned)(v >> 32), m, 64);
    return ((unsigned long long)(unsigned)hi << 32) | (unsigned)lo;
}

// ---------------------------------------------------------------------------
// init: residual R (d_out quantized region) = x; zero losses; init winners
// ---------------------------------------------------------------------------
__global__ void rvq_init_kernel(const float* __restrict__ x, float* __restrict__ out,
                                unsigned long long* __restrict__ winners) {
    int i = blockIdx.x * blockDim.x + threadIdx.x;
    const float4* x4 = (const float4*)x;
    float4* r4 = (float4*)(out + QOUT_OFF);
    const int n4 = BN * D / 4;
    for (int k = i; k < n4; k += gridDim.x * blockDim.x)
        r4[k] = x4[k];
    if (i < BN) winners[i] = ~0ull;
    if (i < NUM_Q) out[LOSS_OFF + i] = 0.0f;
}

// ---------------------------------------------------------------------------
// e2: per-codeword squared norms for all layers. one wave per codeword row.
// ---------------------------------------------------------------------------
__global__ void rvq_e2_kernel(const float* __restrict__ cbs, float* __restrict__ e2ws) {
    const int row = blockIdx.x;          // 0 .. NUM_Q*C-1
    const int lane = threadIdx.x;        // 0..63
    const float* p = cbs + (size_t)row * D + lane * 8;
    float4 a = *(const float4*)p;
    float4 b = *(const float4*)(p + 4);
    float ss = a.x*a.x + a.y*a.y + a.z*a.z + a.w*a.w
             + b.x*b.x + b.y*b.y + b.z*b.z + b.w*b.w;
#pragma unroll
    for (int off = 32; off >= 1; off >>= 1) ss += __shfl_xor(ss, off, 64);
    if (lane == 0) e2ws[row] = ss;
}

// ---------------------------------------------------------------------------
// score GEMM + argmin: dist-relevant score = e2[n] - 2*dot(R[m], CB[n])
// fp16 hi/lo 3-pass MFMA (hh + hl + lh); per-token winner via u64 atomicMin.
// block: 128 tokens x 128 codewords; 8 waves, wave tile 64x32
// ---------------------------------------------------------------------------
__global__ __launch_bounds__(GTHREADS, 4) void rvq_score_kernel(
    const float* __restrict__ cb,        // this layer's codebook [C][D]
    const float* __restrict__ R,         // residual [BN][D]
    const float* __restrict__ e2,        // this layer's e2 [C]
    unsigned long long* __restrict__ winners)
{
    __shared__ __align__(16) _Float16 AsHi[TM][LDK];
    __shared__ __align__(16) _Float16 AsLo[TM][LDK];
    __shared__ __align__(16) _Float16 BsHi[TN][LDK];
    __shared__ __align__(16) _Float16 BsLo[TN][LDK];
    __shared__ unsigned long long part[4][TM];

    const int tid  = threadIdx.x;
    const int lane = tid & 63;
    const int wv   = tid >> 6;
    const int wm   = wv & 1;     // 0..1 : which 64-token half
    const int wn   = wv >> 1;    // 0..3 : which 32-codeword slice
    const int lm   = lane & 15;
    const int lq   = lane >> 4;

    // swizzle: the 8 n-blocks sharing one A tile land on the same XCD
    const int mg = blockIdx.x & 63;
    const int nb = blockIdx.x >> 6;
    const int tok0 = mg * TM;
    const int cb0  = nb * TN;

    const int srow = tid >> 2;   // staging row 0..127
    const int skq  = tid & 3;    // which 8-elem k-octet

    const float* Ag = R  + (size_t)(tok0 + srow) * D + skq * 8;
    const float* Bg = cb + (size_t)(cb0  + srow) * D + skq * 8;

    f32x4 acc[4][2];
#pragma unroll
    for (int mt = 0; mt < 4; ++mt)
#pragma unroll
        for (int nt = 0; nt < 2; ++nt)
            acc[mt][nt] = (f32x4){0.f, 0.f, 0.f, 0.f};

    for (int kb = 0; kb < D / BKK; ++kb) {
        const int kc = kb * BKK;
        float4 a0 = *(const float4*)(Ag + kc);
        float4 a1 = *(const float4*)(Ag + kc + 4);
        float4 b0 = *(const float4*)(Bg + kc);
        float4 b1 = *(const float4*)(Bg + kc + 4);

        __syncthreads();   // previous iteration's LDS reads complete

        {
            float av[8] = {a0.x, a0.y, a0.z, a0.w, a1.x, a1.y, a1.z, a1.w};
            f16x8 h, l;
#pragma unroll
            for (int i = 0; i < 8; ++i) {
                _Float16 hi = (_Float16)av[i];
                h[i] = hi;
                l[i] = (_Float16)(av[i] - (float)hi);
            }
            *(f16x8*)&AsHi[srow][skq * 8] = h;
            *(f16x8*)&AsLo[srow][skq * 8] = l;
        }
        {
            float bv[8] = {b0.x, b0.y, b0.z, b0.w, b1.x, b1.y, b1.z, b1.w};
            f16x8 h, l;
#pragma unroll
            for (int i = 0; i < 8; ++i) {
                _Float16 hi = (_Float16)bv[i];
                h[i] = hi;
                l[i] = (_Float16)(bv[i] - (float)hi);
            }
            *(f16x8*)&BsHi[srow][skq * 8] = h;
            *(f16x8*)&BsLo[srow][skq * 8] = l;
        }
        __syncthreads();

        f16x8 ah[4], al[4], bh[2], bl[2];
#pragma unroll
        for (int mt = 0; mt < 4; ++mt) {
            ah[mt] = *(const f16x8*)&AsHi[wm * 64 + mt * 16 + lm][lq * 8];
            al[mt] = *(const f16x8*)&AsLo[wm * 64 + mt * 16 + lm][lq * 8];
        }
#pragma unroll
        for (int nt = 0; nt < 2; ++nt) {
            bh[nt] = *(const f16x8*)&BsHi[wn * 32 + nt * 16 + lm][lq * 8];
            bl[nt] = *(const f16x8*)&BsLo[wn * 32 + nt * 16 + lm][lq * 8];
        }
#pragma unroll
        for (int mt = 0; mt < 4; ++mt)
#pragma unroll
            for (int nt = 0; nt < 2; ++nt)
                acc[mt][nt] = __builtin_amdgcn_mfma_f32_16x16x32_f16(ah[mt], bh[nt], acc[mt][nt], 0, 0, 0);
#pragma unroll
        for (int mt = 0; mt < 4; ++mt)
#pragma unroll
            for (int nt = 0; nt < 2; ++nt)
                acc[mt][nt] = __builtin_amdgcn_mfma_f32_16x16x32_f16(ah[mt], bl[nt], acc[mt][nt], 0, 0, 0);
#pragma unroll
        for (int mt = 0; mt < 4; ++mt)
#pragma unroll
            for (int nt = 0; nt < 2; ++nt)
                acc[mt][nt] = __builtin_amdgcn_mfma_f32_16x16x32_f16(al[mt], bh[nt], acc[mt][nt], 0, 0, 0);
    }

    // ---- epilogue: score, pack, per-token argmin ----
    const int n0 = cb0 + wn * 32 + lm;         // nt=0 column
    const float e2v0 = e2[n0];
    const float e2v1 = e2[n0 + 16];

#pragma unroll
    for (int mt = 0; mt < 4; ++mt) {
#pragma unroll
        for (int r = 0; r < 4; ++r) {
            float s0 = e2v0 - 2.0f * acc[mt][0][r];
            float s1 = e2v1 - 2.0f * acc[mt][1][r];
            unsigned long long p0 = ((unsigned long long)fkey(s0) << 32) | (unsigned)n0;
            unsigned long long p1 = ((unsigned long long)fkey(s1) << 32) | (unsigned)(n0 + 16);
            unsigned long long p = u64min(p0, p1);
#pragma unroll
            for (int off = 1; off < 16; off <<= 1)
                p = u64min(p, shfl_xor_u64(p, off));
            if (lm == 0)
                part[wn][wm * 64 + mt * 16 + lq * 4 + r] = p;
        }
    }
    __syncthreads();
    if (tid < TM) {
        unsigned long long p = part[0][tid];
        p = u64min(p, part[1][tid]);
        p = u64min(p, part[2][tid]);
        p = u64min(p, part[3][tid]);
        atomicMin(&winners[tok0 + tid], p);
    }
}

// ---------------------------------------------------------------------------
// update: residual -= chosen codeword; loss partial; emit index; reset winner
// 16 tokens/block, 16 threads/token
// ---------------------------------------------------------------------------
__global__ __launch_bounds__(256) void rvq_update_kernel(
    const float* __restrict__ cb, float* __restrict__ out,
    unsigned long long* __restrict__ winners, int q)
{
    __shared__ float lsum[4];
    const int tid = threadIdx.x;
    const int tl  = tid >> 4;
    const int g   = tid & 15;
    const int tok = blockIdx.x * 16 + tl;

    float* R = out + QOUT_OFF;
    unsigned long long w = winners[tok];
    const int best = (int)(unsigned)(w & 0xFFFFFFFFull);
    const float* crow = cb + (size_t)best * D;
    float* rrow = R + (size_t)tok * D;

    float ss = 0.0f;
#pragma unroll
    for (int m = 0; m < 8; ++m) {
        const int off = (m * 16 + g) * 4;
        float4 r = *(const float4*)&rrow[off];
        float4 c = *(const float4*)&crow[off];
        float4 nr = make_float4(r.x - c.x, r.y - c.y, r.z - c.z, r.w - c.w);
        *(float4*)&rrow[off] = nr;
        ss += nr.x * nr.x + nr.y * nr.y + nr.z * nr.z + nr.w * nr.w;
    }
    if (g == 0) {
        out[IDX_OFF + (size_t)tok * NUM_Q + q] = (float)best;
        winners[tok] = ~0ull;   // ready for next layer
    }
#pragma unroll
    for (int off = 32; off >= 1; off >>= 1) ss += __shfl_xor(ss, off, 64);
    if ((tid & 63) == 0) lsum[tid >> 6] = ss;
    __syncthreads();
    if (tid == 0)
        atomicAdd(out + LOSS_OFF + q, lsum[0] + lsum[1] + lsum[2] + lsum[3]);
}

// ---------------------------------------------------------------------------
// finalize: quantized_out = x - residual_final (in place); scale losses
// ---------------------------------------------------------------------------
__global__ void rvq_finalize_kernel(const float* __restrict__ x, float* __restrict__ out) {
    int i = blockIdx.x * blockDim.x + threadIdx.x;
    const float4* x4 = (const float4*)x;
    float4* o4 = (float4*)(out + QOUT_OFF);
    const int n4 = BN * D / 4;
    for (int k = i; k < n4; k += gridDim.x * blockDim.x) {
        float4 xv = x4[k];
        float4 rv = o4[k];
        o4[k] = make_float4(xv.x - rv.x, xv.y - rv.y, xv.z - rv.z, xv.w - rv.w);
    }
    if (i < NUM_Q) out[LOSS_OFF + i] *= (1.0f / (float)(BN * D));
}

extern "C" void kernel_launch(void* const* d_in, const int* in_sizes, int n_in,
                              void* d_out, int out_size, void* d_ws, size_t ws_size,
                              hipStream_t stream) {
    const float* x   = (const float*)d_in[0];
    const float* cbs = (const float*)d_in[1];
    float* out = (float*)d_out;
    unsigned long long* winners = (unsigned long long*)((char*)d_ws + WIN_OFF_B);
    float* e2ws = (float*)((char*)d_ws + E2_OFF_B);

    hipLaunchKernelGGL(rvq_init_kernel, dim3(1024), dim3(256), 0, stream, x, out, winners);
    hipLaunchKernelGGL(rvq_e2_kernel, dim3(NUM_Q * C), dim3(64), 0, stream, cbs, e2ws);

    float* R = out + QOUT_OFF;
    for (int q = 0; q < NUM_Q; ++q) {
        const float* cb_q = cbs + (size_t)q * C * D;
        hipLaunchKernelGGL(rvq_score_kernel, dim3((BN / TM) * (C / TN)), dim3(GTHREADS), 0, stream,
                           cb_q, R, e2ws + (size_t)q * C, winners);
        hipLaunchKernelGGL(rvq_update_kernel, dim3(BN / 16), dim3(256), 0, stream,
                           cb_q, out, winners, q);
    }
    hipLaunchKernelGGL(rvq_finalize_kernel, dim3(1024), dim3(256), 0, stream, x, out);
}